// Round 8
// baseline (169.746 us; speedup 1.0000x reference)
//
#include <hip/hip_runtime.h>

// Problem constants (match reference setup_inputs).
#define N_NODES 50000
#define N_EDGES 200000
#define OUT 32
#define IN_SELF 128
#define EDGE_DIM 16

// ---------------------------------------------------------------------------
// Kernel 0: fold W_edge/b_edge over i:  Wcol[j][k] = sum_i W_edge[(i*32+j)*16+k]
//           bcol[j] = sum_i b_edge[i*32+j]
// One block, trivial cost.
// ---------------------------------------------------------------------------
__global__ void prep_kernel(const float* __restrict__ W_edge,
                            const float* __restrict__ b_edge,
                            float* __restrict__ Wcol, float* __restrict__ bcol) {
    int t = threadIdx.x;
    if (t < OUT * EDGE_DIM) {
        int j = t / EDGE_DIM, k = t % EDGE_DIM;
        float s = 0.f;
#pragma unroll
        for (int i = 0; i < OUT; ++i) s += W_edge[(i * OUT + j) * EDGE_DIM + k];
        Wcol[t] = s;
    }
    if (t < OUT) {
        float s = 0.f;
#pragma unroll
        for (int i = 0; i < OUT; ++i) s += b_edge[i * OUT + t];
        bcol[t] = s;
    }
}

// ---------------------------------------------------------------------------
// Kernel 1: per-edge message + scatter.
// 256 threads = 8 edges x 32 lanes. lane j computes
//   s = h_neigh[src][j] * (ef[e] . Wcol[j] + bcol[j])
// and atomically adds into agg[dst*32+j]; lane 0 bumps deg[dst].
// Wcol staged in LDS padded to 17 (stride-16 would be a 16-way bank conflict).
// BUGFIX r3: wl has 512 elements but block is 256 threads — must load with a
// strided loop, not `if (t < 512)` (rows 16..31 were uninitialized LDS).
// ---------------------------------------------------------------------------
__global__ void edge_kernel(const float* __restrict__ h_neigh,
                            const float* __restrict__ ef,
                            const int* __restrict__ src,
                            const int* __restrict__ dst,
                            const float* __restrict__ Wcol,
                            const float* __restrict__ bcol,
                            float* __restrict__ agg,
                            float* __restrict__ deg, int E) {
    __shared__ float wl[OUT][EDGE_DIM + 1];
    __shared__ float bl[OUT];
    __shared__ float efl[8][EDGE_DIM];
    int t = threadIdx.x;
    for (int i = t; i < OUT * EDGE_DIM; i += 256)
        wl[i / EDGE_DIM][i % EDGE_DIM] = Wcol[i];
    if (t < OUT) bl[t] = bcol[t];
    int e0 = blockIdx.x * 8;
    if (t < 8 * EDGE_DIM) {
        int e = e0 + t / EDGE_DIM;
        if (e < E) efl[t / EDGE_DIM][t % EDGE_DIM] = ef[e * EDGE_DIM + t % EDGE_DIM];
    }
    __syncthreads();

    int le = t >> 5, j = t & 31;
    int e = e0 + le;
    if (e >= E) return;
    int s = src[e];
    int d = dst[e];
    float acc = bl[j];
#pragma unroll
    for (int k = 0; k < EDGE_DIM; ++k) acc += efl[le][k] * wl[j][k];
    float hv = h_neigh[s * OUT + j];
    atomicAdd(&agg[d * OUT + j], hv * acc);
    if (j == 0) atomicAdd(&deg[d], 1.0f);
}

// ---------------------------------------------------------------------------
// Kernel 2: node phase.  z[n,j] = relu( h_self[n].W_self[j] + aggN[n].W_neigh[j] )
// 256 threads = 8 nodes x 32 lanes; lane j computes output j.
// W_self in LDS padded to 129 (stride-128 => 32-way conflict otherwise),
// W_neigh padded to 33. h_self rows broadcast-read from LDS (free).
// ---------------------------------------------------------------------------
__global__ void node_kernel(const float* __restrict__ h_self,
                            const float* __restrict__ agg,
                            const float* __restrict__ deg,
                            const float* __restrict__ W_self,
                            const float* __restrict__ W_neigh,
                            float* __restrict__ out, int N) {
    __shared__ float ws[OUT][IN_SELF + 1];   // 16.5 KB
    __shared__ float wn[OUT][OUT + 1];       // 4.2 KB
    __shared__ float hs[8][IN_SELF];         // 4 KB
    __shared__ float an[8][OUT];             // 1 KB
    int t = threadIdx.x;
    for (int i = t; i < OUT * IN_SELF; i += 256) ws[i >> 7][i & 127] = W_self[i];
    for (int i = t; i < OUT * OUT; i += 256) wn[i >> 5][i & 31] = W_neigh[i];
    int n0 = blockIdx.x * 8;
    for (int i = t; i < 8 * IN_SELF; i += 256) {
        int n = n0 + (i >> 7);
        if (n < N) hs[i >> 7][i & 127] = h_self[n * IN_SELF + (i & 127)];
    }
    {
        int n = n0 + (t >> 5);
        if (n < N) {
            float dg = fmaxf(deg[n], 1.0f);
            an[t >> 5][t & 31] = agg[n * OUT + (t & 31)] / dg;
        }
    }
    __syncthreads();

    int ln = t >> 5, j = t & 31;
    int n = n0 + ln;
    if (n >= N) return;
    float acc = 0.f;
#pragma unroll 8
    for (int k = 0; k < IN_SELF; ++k) acc += hs[ln][k] * ws[j][k];
#pragma unroll
    for (int k = 0; k < OUT; ++k) acc += an[ln][k] * wn[j][k];
    out[n * OUT + j] = fmaxf(acc, 0.f);
}

// ---------------------------------------------------------------------------
extern "C" void kernel_launch(void* const* d_in, const int* in_sizes, int n_in,
                              void* d_out, int out_size, void* d_ws, size_t ws_size,
                              hipStream_t stream) {
    const float* h_neigh = (const float*)d_in[0];   // [N,32]
    const float* h_self  = (const float*)d_in[1];   // [N,128]
    const float* ef      = (const float*)d_in[2];   // [E,16]
    const float* W_edge  = (const float*)d_in[3];   // [1024,16]
    const float* b_edge  = (const float*)d_in[4];   // [1024]
    const float* W_self  = (const float*)d_in[5];   // [32,128]
    const float* W_neigh = (const float*)d_in[6];   // [32,32]
    const int*   src     = (const int*)d_in[7];     // [E]
    const int*   dst     = (const int*)d_in[8];     // [E]
    float* out = (float*)d_out;

    const int N = N_NODES, E = N_EDGES;

    // Workspace layout (floats): Wcol[512] | bcol[32] | deg[N] | agg[N*32]
    float* Wcol = (float*)d_ws;
    float* bcol = Wcol + OUT * EDGE_DIM;
    float* deg  = bcol + OUT;
    float* agg  = deg + N;

    // Zero deg+agg (contiguous) every launch — harness poisons ws with 0xAA.
    hipMemsetAsync(deg, 0, (size_t)(N + N * OUT) * sizeof(float), stream);

    prep_kernel<<<1, 512, 0, stream>>>(W_edge, b_edge, Wcol, bcol);

    edge_kernel<<<(E + 7) / 8, 256, 0, stream>>>(h_neigh, ef, src, dst, Wcol, bcol,
                                                 agg, deg, E);

    node_kernel<<<(N + 7) / 8, 256, 0, stream>>>(h_self, agg, deg, W_self, W_neigh,
                                                 out, N);
}

// Round 12
// 150.818 us; speedup vs baseline: 1.1255x; 1.1255x over previous
//
#include <hip/hip_runtime.h>

// Problem constants (match reference setup_inputs).
#define N_NODES 50000
#define N_EDGES 200000
#define OUT 32
#define IN_SELF 128
#define EDGE_DIM 16

// ---------------------------------------------------------------------------
// Kernel 0: fused zero + prep.
// All blocks grid-stride-zero deg+agg (float4); block 0 additionally folds
// W_edge/b_edge over i: Wcol[j][k] = sum_i W_edge[(i*32+j)*16+k],
// bcol[j] = sum_i b_edge[i*32+j].
// Replaces the hipMemsetAsync graph node (suspected ~20-30us slow path) +
// separate prep dispatch with ONE kernel dispatch.
// ---------------------------------------------------------------------------
__global__ __launch_bounds__(256) void prep_zero_kernel(
        const float* __restrict__ W_edge, const float* __restrict__ b_edge,
        float* __restrict__ Wcol, float* __restrict__ bcol,
        float4* __restrict__ zero4, int n_zero4) {
    int gid = blockIdx.x * 256 + threadIdx.x;
    for (int i = gid; i < n_zero4; i += gridDim.x * 256) {
        zero4[i] = make_float4(0.f, 0.f, 0.f, 0.f);
    }
    if (blockIdx.x == 0) {
        int t = threadIdx.x;
        for (int i = t; i < OUT * EDGE_DIM; i += 256) {
            int j = i / EDGE_DIM, k = i % EDGE_DIM;
            float s = 0.f;
#pragma unroll
            for (int r = 0; r < OUT; ++r) s += W_edge[(r * OUT + j) * EDGE_DIM + k];
            Wcol[i] = s;
        }
        if (t < OUT) {
            float s = 0.f;
#pragma unroll
            for (int r = 0; r < OUT; ++r) s += b_edge[r * OUT + t];
            bcol[t] = s;
        }
    }
}

// ---------------------------------------------------------------------------
// Kernel 1: per-edge message + scatter. 32 edges per 256-thread block
// (4 edges per thread) to amortize Wcol/bcol staging; ef staged as float4.
// lane j: s = h_neigh[src][j] * (ef[e].Wcol[j] + bcol[j]) -> atomicAdd agg.
// wl4 stride 5 float4 (20 dwords): lanes j,j+8 share bank-quad = structural
// minimum for b128; efl reads are wave-broadcast.
// ---------------------------------------------------------------------------
__global__ __launch_bounds__(256) void edge_kernel(
        const float* __restrict__ h_neigh, const float* __restrict__ ef,
        const int* __restrict__ src, const int* __restrict__ dst,
        const float* __restrict__ Wcol, const float* __restrict__ bcol,
        float* __restrict__ agg, float* __restrict__ deg, int E) {
    __shared__ float4 wl4[OUT][5];     // 16 floats + 1 float4 pad per row
    __shared__ float4 efl[32][4];      // 32 edges x 16 floats
    __shared__ float bl[OUT];
    __shared__ int sdl[32], ddl[32];

    int t = threadIdx.x;
    int e0 = blockIdx.x * 32;
    if (t < 128) {
        wl4[t >> 2][t & 3] = ((const float4*)Wcol)[t];
    } else {
        int i = t - 128;                              // 0..127
        int e = e0 + (i >> 2);
        if (e < E) efl[i >> 2][i & 3] = ((const float4*)ef)[(size_t)e * 4 + (i & 3)];
    }
    if (t < 32) {
        bl[t] = bcol[t];
        sdl[t] = (e0 + t < E) ? src[e0 + t] : 0;
    } else if (t < 64) {
        int i = t - 32;
        ddl[i] = (e0 + i < E) ? dst[e0 + i] : 0;
    }
    __syncthreads();

    int g = t >> 5, j = t & 31;
#pragma unroll
    for (int it = 0; it < 4; ++it) {
        int le = g + 8 * it;          // 0..31
        int e = e0 + le;
        if (e >= E) continue;
        int s = sdl[le];
        int d = ddl[le];
        float4 w0 = wl4[j][0], w1 = wl4[j][1], w2 = wl4[j][2], w3 = wl4[j][3];
        float4 f0 = efl[le][0], f1 = efl[le][1], f2 = efl[le][2], f3 = efl[le][3];
        float acc = bl[j];
        acc = fmaf(f0.x, w0.x, acc); acc = fmaf(f0.y, w0.y, acc);
        acc = fmaf(f0.z, w0.z, acc); acc = fmaf(f0.w, w0.w, acc);
        acc = fmaf(f1.x, w1.x, acc); acc = fmaf(f1.y, w1.y, acc);
        acc = fmaf(f1.z, w1.z, acc); acc = fmaf(f1.w, w1.w, acc);
        acc = fmaf(f2.x, w2.x, acc); acc = fmaf(f2.y, w2.y, acc);
        acc = fmaf(f2.z, w2.z, acc); acc = fmaf(f2.w, w2.w, acc);
        acc = fmaf(f3.x, w3.x, acc); acc = fmaf(f3.y, w3.y, acc);
        acc = fmaf(f3.z, w3.z, acc); acc = fmaf(f3.w, w3.w, acc);
        float hv = h_neigh[(size_t)s * OUT + j];
        atomicAdd(&agg[(size_t)d * OUT + j], hv * acc);
        if (j == 0) atomicAdd(&deg[d], 1.0f);
    }
}

// ---------------------------------------------------------------------------
// Kernel 2: node phase, float4 everywhere (ds_read_b128 instead of b32).
// z[n,j] = relu(h_self[n].W_self[j] + (agg[n]/deg).W_neigh[j])
// 256 threads = 8 nodes x 32 lanes. ws4 rows padded to 33 float4 so lanes
// 0..7 cover distinct bank-quads (structural-minimum b128 access).
// ---------------------------------------------------------------------------
__global__ __launch_bounds__(256) void node_kernel(
        const float* __restrict__ h_self, const float* __restrict__ agg,
        const float* __restrict__ deg, const float* __restrict__ W_self,
        const float* __restrict__ W_neigh, float* __restrict__ out, int N) {
    __shared__ float4 ws4[OUT][33];   // 32 data + 1 pad   (16.9 KB)
    __shared__ float4 wn4[OUT][9];    // 8 data + 1 pad    (4.6 KB)
    __shared__ float4 hs4[8][32];     // 8 nodes x 128     (4 KB)
    __shared__ float4 an4[8][8];      // 8 nodes x 32      (1 KB)

    int t = threadIdx.x;
    int n0 = blockIdx.x * 8;

    for (int i = t; i < OUT * (IN_SELF / 4); i += 256)      // 1024 float4
        ws4[i >> 5][i & 31] = ((const float4*)W_self)[i];
    {                                                        // 256 float4
        wn4[t >> 3][t & 7] = ((const float4*)W_neigh)[t];
    }
    {                                                        // 256 float4
        int n = n0 + (t >> 5);
        if (n < N) hs4[t >> 5][t & 31] = ((const float4*)h_self)[(size_t)n0 * 32 + t];
    }
    if (t < 64) {                                            // 64 float4
        int ln = t >> 3, k4 = t & 7;
        int n = n0 + ln;
        if (n < N) {
            float r = 1.0f / fmaxf(deg[n], 1.0f);
            float4 v = ((const float4*)agg)[(size_t)n * 8 + k4];
            an4[ln][k4] = make_float4(v.x * r, v.y * r, v.z * r, v.w * r);
        }
    }
    __syncthreads();

    int ln = t >> 5, j = t & 31;
    int n = n0 + ln;
    if (n >= N) return;
    float4 a4 = make_float4(0.f, 0.f, 0.f, 0.f);
#pragma unroll
    for (int k4 = 0; k4 < IN_SELF / 4; ++k4) {
        float4 h = hs4[ln][k4], w = ws4[j][k4];
        a4.x = fmaf(h.x, w.x, a4.x); a4.y = fmaf(h.y, w.y, a4.y);
        a4.z = fmaf(h.z, w.z, a4.z); a4.w = fmaf(h.w, w.w, a4.w);
    }
#pragma unroll
    for (int k4 = 0; k4 < OUT / 4; ++k4) {
        float4 h = an4[ln][k4], w = wn4[j][k4];
        a4.x = fmaf(h.x, w.x, a4.x); a4.y = fmaf(h.y, w.y, a4.y);
        a4.z = fmaf(h.z, w.z, a4.z); a4.w = fmaf(h.w, w.w, a4.w);
    }
    float acc = (a4.x + a4.y) + (a4.z + a4.w);
    out[(size_t)n * OUT + j] = fmaxf(acc, 0.f);
}

// ---------------------------------------------------------------------------
extern "C" void kernel_launch(void* const* d_in, const int* in_sizes, int n_in,
                              void* d_out, int out_size, void* d_ws, size_t ws_size,
                              hipStream_t stream) {
    const float* h_neigh = (const float*)d_in[0];   // [N,32]
    const float* h_self  = (const float*)d_in[1];   // [N,128]
    const float* ef      = (const float*)d_in[2];   // [E,16]
    const float* W_edge  = (const float*)d_in[3];   // [1024,16]
    const float* b_edge  = (const float*)d_in[4];   // [1024]
    const float* W_self  = (const float*)d_in[5];   // [32,128]
    const float* W_neigh = (const float*)d_in[6];   // [32,32]
    const int*   src     = (const int*)d_in[7];     // [E]
    const int*   dst     = (const int*)d_in[8];     // [E]
    float* out = (float*)d_out;

    const int N = N_NODES, E = N_EDGES;

    // Workspace layout (floats): Wcol[512] | bcol[32] | deg[N] | agg[N*32]
    // deg offset = 544 floats (2176 B) -> float4-aligned for the zero pass.
    float* Wcol = (float*)d_ws;
    float* bcol = Wcol + OUT * EDGE_DIM;
    float* deg  = bcol + OUT;
    float* agg  = deg + N;

    const int n_zero4 = (N + N * OUT) / 4;          // 412500 float4 = 6.6 MB
    const int zgrid = (n_zero4 + 255) / 256;        // 1612 blocks

    prep_zero_kernel<<<zgrid, 256, 0, stream>>>(W_edge, b_edge, Wcol, bcol,
                                                (float4*)deg, n_zero4);

    edge_kernel<<<(E + 31) / 32, 256, 0, stream>>>(h_neigh, ef, src, dst,
                                                   Wcol, bcol, agg, deg, E);

    node_kernel<<<(N + 7) / 8, 256, 0, stream>>>(h_self, agg, deg, W_self,
                                                 W_neigh, out, N);
}

// Round 13
// 146.207 us; speedup vs baseline: 1.1610x; 1.0315x over previous
//
#include <hip/hip_runtime.h>

// Problem constants (match reference setup_inputs).
#define N_NODES 50000
#define N_EDGES 200000
#define OUT 32
#define IN_SELF 128
#define EDGE_DIM 16

// ---------------------------------------------------------------------------
// Kernel 0: init head[] = -1 (linked-list stacks, 200 KB — replaces the old
// 6.6 MB agg zero) ; block 0 folds W_edge/b_edge over i:
//   Wcol[j][k] = sum_i W_edge[(i*32+j)*16+k],  bcol[j] = sum_i b_edge[i*32+j]
// ---------------------------------------------------------------------------
__global__ __launch_bounds__(256) void init_prep_kernel(
        const float* __restrict__ W_edge, const float* __restrict__ b_edge,
        float* __restrict__ Wcol, float* __restrict__ bcol,
        int* __restrict__ head, int n_head) {
    int gid = blockIdx.x * 256 + threadIdx.x;
    for (int i = gid; i < n_head; i += gridDim.x * 256) head[i] = -1;
    if (blockIdx.x == 0) {
        int t = threadIdx.x;
        for (int i = t; i < OUT * EDGE_DIM; i += 256) {
            int j = i / EDGE_DIM, k = i % EDGE_DIM;
            float s = 0.f;
#pragma unroll
            for (int r = 0; r < OUT; ++r) s += W_edge[(r * OUT + j) * EDGE_DIM + k];
            Wcol[i] = s;
        }
        if (t < OUT) {
            float s = 0.f;
#pragma unroll
            for (int r = 0; r < OUT; ++r) s += b_edge[r * OUT + t];
            bcol[t] = s;
        }
    }
}

// ---------------------------------------------------------------------------
// Kernel 1: edge message kernel — NO f32 atomics. 32 edges per 256-thread
// block (4 per thread). lane j computes s = h_src[j]*(ef.Wcol[j]+bcol[j]) and
// stores it to ES[e][j] (coalesced 128B row). Lane 0 pushes e onto dst's
// lock-free stack: nxt[e] = atomicExch(&head[d], e)  (200K int atomics total
// vs 6.4M f32 atomicAdds in the scatter design).
// ---------------------------------------------------------------------------
__global__ __launch_bounds__(256) void edge_kernel(
        const float* __restrict__ h_neigh, const float* __restrict__ ef,
        const int* __restrict__ src, const int* __restrict__ dst,
        const float* __restrict__ Wcol, const float* __restrict__ bcol,
        float* __restrict__ ES, int* __restrict__ head, int* __restrict__ nxt,
        int E) {
    __shared__ float4 wl4[OUT][5];     // 16 floats + 1 float4 pad per row
    __shared__ float4 efl[32][4];      // 32 edges x 16 floats
    __shared__ float bl[OUT];
    __shared__ int sdl[32], ddl[32];

    int t = threadIdx.x;
    int e0 = blockIdx.x * 32;
    if (t < 128) {
        wl4[t >> 2][t & 3] = ((const float4*)Wcol)[t];
    } else {
        int i = t - 128;                              // 0..127
        int e = e0 + (i >> 2);
        if (e < E) efl[i >> 2][i & 3] = ((const float4*)ef)[(size_t)e * 4 + (i & 3)];
    }
    if (t < 32) {
        bl[t] = bcol[t];
        sdl[t] = (e0 + t < E) ? src[e0 + t] : 0;
    } else if (t < 64) {
        int i = t - 32;
        ddl[i] = (e0 + i < E) ? dst[e0 + i] : 0;
    }
    __syncthreads();

    int g = t >> 5, j = t & 31;
#pragma unroll
    for (int it = 0; it < 4; ++it) {
        int le = g + 8 * it;          // 0..31
        int e = e0 + le;
        if (e >= E) continue;
        int s = sdl[le];
        int d = ddl[le];
        float4 w0 = wl4[j][0], w1 = wl4[j][1], w2 = wl4[j][2], w3 = wl4[j][3];
        float4 f0 = efl[le][0], f1 = efl[le][1], f2 = efl[le][2], f3 = efl[le][3];
        float acc = bl[j];
        acc = fmaf(f0.x, w0.x, acc); acc = fmaf(f0.y, w0.y, acc);
        acc = fmaf(f0.z, w0.z, acc); acc = fmaf(f0.w, w0.w, acc);
        acc = fmaf(f1.x, w1.x, acc); acc = fmaf(f1.y, w1.y, acc);
        acc = fmaf(f1.z, w1.z, acc); acc = fmaf(f1.w, w1.w, acc);
        acc = fmaf(f2.x, w2.x, acc); acc = fmaf(f2.y, w2.y, acc);
        acc = fmaf(f2.z, w2.z, acc); acc = fmaf(f2.w, w2.w, acc);
        acc = fmaf(f3.x, w3.x, acc); acc = fmaf(f3.y, w3.y, acc);
        acc = fmaf(f3.z, w3.z, acc); acc = fmaf(f3.w, w3.w, acc);
        float hv = h_neigh[(size_t)s * OUT + j];
        ES[(size_t)e * OUT + j] = hv * acc;          // coalesced 128B row
        if (j == 0) {
            int old = atomicExch(&head[d], e);       // lock-free stack push
            nxt[e] = old;
        }
    }
}

// ---------------------------------------------------------------------------
// Kernel 2: node phase. 256 threads = 8 nodes x 32 lanes.
// Each 32-lane group walks its node's edge chain, summing ES rows (lane j
// sums component j; chain length = in-degree, counted on the fly -> no deg
// array). Then z[n,j] = relu(h_self[n].W_self[j] + (sum/deg).W_neigh[j])
// with the float4 LDS GEMV from r12 (padded strides, conflict-free).
// ---------------------------------------------------------------------------
__global__ __launch_bounds__(256) void node_kernel(
        const float* __restrict__ h_self, const float* __restrict__ ES,
        const int* __restrict__ head, const int* __restrict__ nxt,
        const float* __restrict__ W_self, const float* __restrict__ W_neigh,
        float* __restrict__ out, int N) {
    __shared__ float4 ws4[OUT][33];   // 32 data + 1 pad   (16.9 KB)
    __shared__ float4 wn4[OUT][9];    // 8 data + 1 pad    (4.6 KB)
    __shared__ float4 hs4[8][32];     // 8 nodes x 128     (4 KB)
    __shared__ float ans[8][32];      // per-node agg (rows 128B -> f4-aligned)

    int t = threadIdx.x;
    int n0 = blockIdx.x * 8;

    for (int i = t; i < OUT * (IN_SELF / 4); i += 256)      // 1024 float4
        ws4[i >> 5][i & 31] = ((const float4*)W_self)[i];
    wn4[t >> 3][t & 7] = ((const float4*)W_neigh)[t];        // 256 float4
    {                                                        // 256 float4
        int n = n0 + (t >> 5);
        if (n < N) hs4[t >> 5][t & 31] = ((const float4*)h_self)[(size_t)n0 * 32 + t];
    }

    int ln = t >> 5, j = t & 31;
    int n = n0 + ln;
    if (n < N) {
        float aggv = 0.f;
        int cnt = 0;
        int e = head[n];                      // broadcast load per group
        while (e >= 0) {
            aggv += ES[(size_t)e * OUT + j];  // coalesced 128B row gather
            ++cnt;
            e = nxt[e];                       // broadcast load
        }
        ans[ln][j] = aggv / (float)max(cnt, 1);
    }
    __syncthreads();

    if (n >= N) return;
    float4 a4 = make_float4(0.f, 0.f, 0.f, 0.f);
#pragma unroll
    for (int k4 = 0; k4 < IN_SELF / 4; ++k4) {
        float4 h = hs4[ln][k4], w = ws4[j][k4];
        a4.x = fmaf(h.x, w.x, a4.x); a4.y = fmaf(h.y, w.y, a4.y);
        a4.z = fmaf(h.z, w.z, a4.z); a4.w = fmaf(h.w, w.w, a4.w);
    }
    const float4* an4 = (const float4*)&ans[ln][0];
#pragma unroll
    for (int k4 = 0; k4 < OUT / 4; ++k4) {
        float4 h = an4[k4], w = wn4[j][k4];
        a4.x = fmaf(h.x, w.x, a4.x); a4.y = fmaf(h.y, w.y, a4.y);
        a4.z = fmaf(h.z, w.z, a4.z); a4.w = fmaf(h.w, w.w, a4.w);
    }
    float acc = (a4.x + a4.y) + (a4.z + a4.w);
    out[(size_t)n * OUT + j] = fmaxf(acc, 0.f);
}

// ---------------------------------------------------------------------------
extern "C" void kernel_launch(void* const* d_in, const int* in_sizes, int n_in,
                              void* d_out, int out_size, void* d_ws, size_t ws_size,
                              hipStream_t stream) {
    const float* h_neigh = (const float*)d_in[0];   // [N,32]
    const float* h_self  = (const float*)d_in[1];   // [N,128]
    const float* ef      = (const float*)d_in[2];   // [E,16]
    const float* W_edge  = (const float*)d_in[3];   // [1024,16]
    const float* b_edge  = (const float*)d_in[4];   // [1024]
    const float* W_self  = (const float*)d_in[5];   // [32,128]
    const float* W_neigh = (const float*)d_in[6];   // [32,32]
    const int*   src     = (const int*)d_in[7];     // [E]
    const int*   dst     = (const int*)d_in[8];     // [E]
    float* out = (float*)d_out;

    const int N = N_NODES, E = N_EDGES;

    // ws layout (4B units): Wcol[512] | bcol[32] | head[N] | nxt[E] | ES[E*32]
    float* Wcol = (float*)d_ws;
    float* bcol = Wcol + OUT * EDGE_DIM;
    int*   head = (int*)(bcol + OUT);
    int*   nxt  = head + N;
    float* ES   = (float*)(nxt + E);   // offset 250544*4 B, 16B-aligned

    init_prep_kernel<<<64, 256, 0, stream>>>(W_edge, b_edge, Wcol, bcol, head, N);

    edge_kernel<<<(E + 31) / 32, 256, 0, stream>>>(h_neigh, ef, src, dst,
                                                   Wcol, bcol, ES, head, nxt, E);

    node_kernel<<<(N + 7) / 8, 256, 0, stream>>>(h_self, ES, head, nxt,
                                                 W_self, W_neigh, out, N);
}